// Round 13
// baseline (761.443 us; speedup 1.0000x reference)
//
#include <hip/hip_runtime.h>

#define N_TOTAL (8 * 32768)   // 262144 rows (2^18)
#define D 128
#define K 1024
#define DECAY 0.8f
#define EPS 1e-7f
#define MARGIN 4e-3f

typedef __attribute__((ext_vector_type(8))) short bf16x8;
typedef __attribute__((ext_vector_type(4))) float f32x4;
union B8 { uint4 u; bf16x8 b; };

#define MFMA(A, B, C) __builtin_amdgcn_mfma_f32_16x16x32_bf16((A), (B), (C), 0, 0, 0)

#define PASS(EHL, X, A0, A1, A2, A3)                        \
    {                                                       \
        B8 a_, b_;                                          \
        a_.u = EHL[0]; b_.u = X[0]; A0 = MFMA(a_.b, b_.b, A0); \
        a_.u = EHL[1]; b_.u = X[1]; A1 = MFMA(a_.b, b_.b, A1); \
        a_.u = EHL[2]; b_.u = X[2]; A2 = MFMA(a_.b, b_.b, A2); \
        a_.u = EHL[3]; b_.u = X[3]; A3 = MFMA(a_.b, b_.b, A3); \
    }

// round-to-nearest-even f32 -> bf16 (bit trick), also returns the fp32 value
__device__ inline unsigned short f2b(float v, float& back) {
    unsigned int u = __float_as_uint(v);
    unsigned int r = (u + 0x7FFFu + ((u >> 16) & 1u)) >> 16;
    back = __uint_as_float(r << 16);
    return (unsigned short)r;
}

// load one row-group's X hi/lo fragments (r5-proven layout):
// lane holds this row, k = 32j + 8q + 0..7
__device__ __forceinline__ void load_x(const float* __restrict__ xp,
                                       uint4* XH, uint4* XL) {
#pragma unroll
    for (int j = 0; j < 4; j++) {
        float4 f0 = *(const float4*)(xp + j * 32);
        float4 f1 = *(const float4*)(xp + j * 32 + 4);
        float fs[8] = {f0.x, f0.y, f0.z, f0.w, f1.x, f1.y, f1.z, f1.w};
        unsigned int hh[4], ll[4];
#pragma unroll
        for (int p = 0; p < 4; p++) {
            float b0, b1, d0, d1;
            unsigned short h0 = f2b(fs[2 * p], b0);
            unsigned short h1 = f2b(fs[2 * p + 1], b1);
            unsigned short s0 = f2b(fs[2 * p] - b0, d0);
            unsigned short s1 = f2b(fs[2 * p + 1] - b1, d1);
            hh[p] = (unsigned int)h0 | ((unsigned int)h1 << 16);
            ll[p] = (unsigned int)s0 | ((unsigned int)s1 << 16);
        }
        XH[j] = make_uint4(hh[0], hh[1], hh[2], hh[3]);
        XL[j] = make_uint4(ll[0], ll[1], ll[2], ll[3]);
    }
}

// ---------------------------------------------------------------------------
// K0 (round-5 proven): ehi/elo bf16 split of embed + e2h = 0.5*||e||^2 fp32
// ---------------------------------------------------------------------------
__global__ __launch_bounds__(128) void k_prep(
    const float* __restrict__ embed, unsigned short* __restrict__ ehi,
    unsigned short* __restrict__ elo, float* __restrict__ e2h) {
    __shared__ float r2[2];
    int c = blockIdx.x, tid = threadIdx.x;
    float v = embed[(size_t)c * D + tid];
    float hb;
    unsigned short h = f2b(v, hb);
    float lb;
    unsigned short l = f2b(v - hb, lb);
    ehi[(size_t)c * D + tid] = h;
    elo[(size_t)c * D + tid] = l;
    float sq = v * v;
    for (int off = 32; off; off >>= 1) sq += __shfl_down(sq, off, 64);
    if ((tid & 63) == 0) r2[tid >> 6] = sq;
    __syncthreads();
    if (tid == 0) e2h[c] = 0.5f * (r2[0] + r2[1]);
}

__global__ __launch_bounds__(256) void k_zero(unsigned int* __restrict__ counts,
                                              unsigned int* __restrict__ rescue_cnt,
                                              float* __restrict__ gsum) {
    int i = blockIdx.x * 256 + threadIdx.x;
    if (i < K) counts[i] = 0u;
    if (i == 0) *rescue_cnt = 0u;
    gsum[i] = 0.f;  // grid exactly covers K*D
}

// ---------------------------------------------------------------------------
// K1: 3-pass hi/lo MFMA screen. Same structure/numerics as r11 (passed),
// but each wave owns TWO row-groups (32 rows) so every E-fragment LDS read
// feeds 2x the MFMAs (LDS-BW was the r11 cap: MfmaUtil 41%).
// Block = 256 thr = 4 waves, 128 rows; supertile = 64 codes, padded LDS.
// ---------------------------------------------------------------------------
__global__ __launch_bounds__(256, 2) void k_screen(
    const float* __restrict__ x, const uint4* __restrict__ ehi4,
    const uint4* __restrict__ elo4, const float* __restrict__ e2h,
    unsigned int* __restrict__ ind, unsigned int* __restrict__ rescue_cnt,
    unsigned int* __restrict__ rescue_list) {
    __shared__ uint4 ebh[2][64 * 17];   // 2 x 17 KB
    __shared__ uint4 ebl[2][64 * 17];   // 2 x 17 KB
    __shared__ float e2s[K];            // 4 KB

    int tid = threadIdx.x;
    int w = tid >> 6, lane = tid & 63;
    int l15 = lane & 15, q = lane >> 4;
    size_t rowA = (size_t)blockIdx.x * 128 + w * 32 + l15;  // group 0
    size_t rowB = rowA + 16;                                // group 1

    for (int i = tid; i < K; i += 256) e2s[i] = e2h[i];

    uint4 xh0[4], xl0[4], xh1[4], xl1[4];
    load_x(x + rowA * D + q * 8, xh0, xl0);
    load_x(x + rowB * D + q * 8, xh1, xl1);

    // ---- prologue: stage supertile 0 (64 codes x 16 uint4 per array)
#pragma unroll
    for (int k2 = 0; k2 < 4; k2++) {
        int i = tid + k2 * 256;
        int c = i >> 4, u = i & 15;
        ebh[0][c * 17 + u] = ehi4[i];
        ebl[0][c * 17 + u] = elo4[i];
    }
    __syncthreads();

    float t1a = -1e30f, t2a = -1e30f, t1b = -1e30f, t2b = -1e30f;
    unsigned int i1a = 0u, i1b = 0u;

    for (int st = 0; st < 16; st++) {
        int b = st & 1;
        // prefetch next supertile into registers (LDS write after compute)
        uint4 rh[4], rl[4];
        if (st < 15) {
            const uint4* gh = ehi4 + (size_t)(st + 1) * 1024;
            const uint4* gl = elo4 + (size_t)(st + 1) * 1024;
#pragma unroll
            for (int k2 = 0; k2 < 4; k2++) {
                rh[k2] = gh[tid + k2 * 256];
                rl[k2] = gl[tid + k2 * 256];
            }
        }

#pragma unroll
        for (int ct = 0; ct < 4; ct++) {
            uint4 eh[4], el[4];
            int cr = (ct * 16 + l15) * 17;
#pragma unroll
            for (int j = 0; j < 4; j++) {
                eh[j] = ebh[b][cr + 4 * j + q];
                el[j] = ebl[b][cr + 4 * j + q];
            }
            // group 0
            f32x4 a0 = {0.f, 0.f, 0.f, 0.f}, a1 = {0.f, 0.f, 0.f, 0.f};
            f32x4 a2 = {0.f, 0.f, 0.f, 0.f}, a3 = {0.f, 0.f, 0.f, 0.f};
            PASS(eh, xh0, a0, a1, a2, a3);
            PASS(el, xh0, a0, a1, a2, a3);
            PASS(eh, xl0, a0, a1, a2, a3);
            // group 1
            f32x4 c0 = {0.f, 0.f, 0.f, 0.f}, c1 = {0.f, 0.f, 0.f, 0.f};
            f32x4 c2 = {0.f, 0.f, 0.f, 0.f}, c3 = {0.f, 0.f, 0.f, 0.f};
            PASS(eh, xh1, c0, c1, c2, c3);
            PASS(el, xh1, c0, c1, c2, c3);
            PASS(eh, xl1, c0, c1, c2, c3);

            int cbase = st * 64 + ct * 16 + q * 4;
            float4 e2q = *(const float4*)&e2s[cbase];
            f32x4 svA = (a0 + a1) + (a2 + a3);
            f32x4 svB = (c0 + c1) + (c2 + c3);
            float vvA[4] = {svA.x - e2q.x, svA.y - e2q.y, svA.z - e2q.z,
                            svA.w - e2q.w};
            float vvB[4] = {svB.x - e2q.x, svB.y - e2q.y, svB.z - e2q.z,
                            svB.w - e2q.w};
#pragma unroll
            for (int r = 0; r < 4; r++) {
                unsigned int c = (unsigned int)(cbase + r);
                float uA = vvA[r];
                bool gA = uA > t1a;
                t2a = fmaxf(t2a, fminf(t1a, uA));
                t1a = fmaxf(t1a, uA);
                i1a = gA ? c : i1a;
                float uB = vvB[r];
                bool gB = uB > t1b;
                t2b = fmaxf(t2b, fminf(t1b, uB));
                t1b = fmaxf(t1b, uB);
                i1b = gB ? c : i1b;
            }
        }

        if (st < 15) {
#pragma unroll
            for (int k2 = 0; k2 < 4; k2++) {
                int i = tid + k2 * 256;
                int c = i >> 4, u = i & 15;
                ebh[b ^ 1][c * 17 + u] = rh[k2];
                ebl[b ^ 1][c * 17 + u] = rl[k2];
            }
        }
        __syncthreads();
    }

    // merge top-2 across the 4 lane-quarters (codes disjoint, same row)
#pragma unroll
    for (int off = 16; off <= 32; off <<= 1) {
        float t1p = __shfl_xor(t1a, off);
        float t2p = __shfl_xor(t2a, off);
        unsigned int i1p = (unsigned int)__shfl_xor((int)i1a, off);
        float nt2 = fmaxf(fminf(t1a, t1p), fmaxf(t2a, t2p));
        unsigned int ni1 = (t1p > t1a || (t1p == t1a && i1p < i1a)) ? i1p : i1a;
        t1a = fmaxf(t1a, t1p);
        t2a = nt2;
        i1a = ni1;
    }
#pragma unroll
    for (int off = 16; off <= 32; off <<= 1) {
        float t1p = __shfl_xor(t1b, off);
        float t2p = __shfl_xor(t2b, off);
        unsigned int i1p = (unsigned int)__shfl_xor((int)i1b, off);
        float nt2 = fmaxf(fminf(t1b, t1p), fmaxf(t2b, t2p));
        unsigned int ni1 = (t1p > t1b || (t1p == t1b && i1p < i1b)) ? i1p : i1b;
        t1b = fmaxf(t1b, t1p);
        t2b = nt2;
        i1b = ni1;
    }
    if (lane < 16) {
        ind[rowA] = i1a;
        if (t1a - t2a < MARGIN) {
            unsigned int pos = atomicAdd(rescue_cnt, 1u);
            rescue_list[pos] = (unsigned int)rowA;
        }
        ind[rowB] = i1b;
        if (t1b - t2b < MARGIN) {
            unsigned int pos = atomicAdd(rescue_cnt, 1u);
            rescue_list[pos] = (unsigned int)rowB;
        }
    }
}

// ---------------------------------------------------------------------------
// K1b (r5-proven): exact fp32 rescore of flagged rows (expected: hundreds)
// ---------------------------------------------------------------------------
__global__ __launch_bounds__(256) void k_rescue(
    const unsigned int* __restrict__ rescue_cnt,
    const unsigned int* __restrict__ rescue_list, const float* __restrict__ x,
    const float* __restrict__ embed, const float* __restrict__ e2h,
    unsigned int* __restrict__ ind) {
    __shared__ float xr[D];
    __shared__ float bv[4];
    __shared__ unsigned int bi[4];
    unsigned int cnt = *rescue_cnt;
    int tid = threadIdx.x;
    for (unsigned int it = blockIdx.x; it < cnt; it += gridDim.x) {
        unsigned int row = rescue_list[it];
        __syncthreads();
        if (tid < D) xr[tid] = x[(size_t)row * D + tid];
        __syncthreads();
        float best = -1e30f;
        unsigned int besti = 0u;
        for (int c = tid; c < K; c += 256) {   // ascending -> strict > = first max
            const float* e = embed + (size_t)c * D;
            float s = 0.f;
            for (int d = 0; d < D; d += 4) {
                float4 xv = *(const float4*)&xr[d];
                float4 ev = *(const float4*)&e[d];
                s += xv.x * ev.x + xv.y * ev.y + xv.z * ev.z + xv.w * ev.w;
            }
            s -= e2h[c];
            if (s > best) { best = s; besti = (unsigned int)c; }
        }
        for (int off = 32; off; off >>= 1) {
            float ov = __shfl_down(best, off, 64);
            unsigned int oi = (unsigned int)__shfl_down((int)besti, off, 64);
            if (ov > best || (ov == best && oi < besti)) { best = ov; besti = oi; }
        }
        if ((tid & 63) == 0) { bv[tid >> 6] = best; bi[tid >> 6] = besti; }
        __syncthreads();
        if (tid == 0) {
            for (int wv = 1; wv < 4; wv++)
                if (bv[wv] > best || (bv[wv] == best && bi[wv] < besti)) {
                    best = bv[wv];
                    besti = bi[wv];
                }
            ind[row] = besti;
        }
    }
}

// ---------------------------------------------------------------------------
// K2: quantize[n][:] = embed[ind[n]][:]  (runs after rescue)
// ---------------------------------------------------------------------------
__global__ __launch_bounds__(256) void k_quant(
    const unsigned int* __restrict__ ind, const float* __restrict__ embed,
    float* __restrict__ q) {
    size_t gid = (size_t)blockIdx.x * 256 + threadIdx.x;  // N*32 threads
    size_t n = gid >> 5;
    int d4 = (int)(gid & 31) << 2;
    unsigned int c = ind[n];
    *(float4*)&q[n * D + d4] = *(const float4*)&embed[(size_t)c * D + d4];
}

// ---------------------------------------------------------------------------
// histogram (after rescue so counts use final ind)
// ---------------------------------------------------------------------------
__global__ __launch_bounds__(256) void k_count(
    const unsigned int* __restrict__ ind, unsigned int* __restrict__ counts) {
    __shared__ unsigned int hist[K];
    int tid = threadIdx.x;
    for (int i = tid; i < K; i += 256) hist[i] = 0u;
    __syncthreads();
    int base = blockIdx.x * 1024;
#pragma unroll
    for (int j = 0; j < 4; j++)
        atomicAdd(&hist[ind[base + j * 256 + tid]], 1u);
    __syncthreads();
    for (int i = tid; i < K; i += 256) {
        unsigned int h = hist[i];
        if (h) atomicAdd(&counts[i], h);
    }
}

__global__ __launch_bounds__(1024) void k_scan(
    const unsigned int* __restrict__ counts, unsigned int* __restrict__ cursor) {
    __shared__ unsigned int tmp[K];
    int tid = threadIdx.x;
    unsigned int v = counts[tid];
    tmp[tid] = v;
    __syncthreads();
    for (int off = 1; off < K; off <<= 1) {
        unsigned int t = (tid >= off) ? tmp[tid - off] : 0u;
        __syncthreads();
        tmp[tid] += t;
        __syncthreads();
    }
    cursor[tid] = tmp[tid] - v;
}

__global__ __launch_bounds__(256) void k_scatter(
    const unsigned int* __restrict__ ind, unsigned int* __restrict__ cursor,
    unsigned int* __restrict__ bucket) {
    unsigned int n = blockIdx.x * 256 + threadIdx.x;
    unsigned int c = ind[n];
    unsigned int pos = atomicAdd(&cursor[c], 1u);
    bucket[pos] = (n << 10) | c;
}

__global__ __launch_bounds__(128) void k_sum2(
    const unsigned int* __restrict__ bucket, const float* __restrict__ x,
    float* __restrict__ gsum) {
    __shared__ unsigned int ent[128];
    int tid = threadIdx.x;
    ent[tid] = bucket[blockIdx.x * 128 + tid];
    __syncthreads();
    float acc = 0.f;
    unsigned int cur = ent[0] & 1023u;
    for (int e = 0; e < 128; e++) {
        unsigned int pk = ent[e];          // uniform across block
        unsigned int c = pk & 1023u;
        unsigned int n = pk >> 10;
        if (c != cur) {                    // block-uniform branch
            atomicAdd(&gsum[(size_t)cur * D + tid], acc);
            acc = 0.f;
            cur = c;
        }
        acc += x[(size_t)n * D + tid];
    }
    atomicAdd(&gsum[(size_t)cur * D + tid], acc);
}

__global__ __launch_bounds__(256) void k_emafin(
    const float* __restrict__ gsum, const unsigned int* __restrict__ counts,
    const float* __restrict__ ema_num, const float* __restrict__ ema_embed,
    float* __restrict__ ema_num_new, float* __restrict__ ema_embed_new) {
    int gid = blockIdx.x * 256 + threadIdx.x;  // K*D threads
    ema_embed_new[gid] = DECAY * ema_embed[gid] + (1.0f - DECAY) * gsum[gid];
    if (gid < K)
        ema_num_new[gid] =
            DECAY * ema_num[gid] + (1.0f - DECAY) * (float)counts[gid];
}

__global__ __launch_bounds__(1024) void k_denom(
    const float* __restrict__ ema_num_new, float* __restrict__ denom) {
    __shared__ float red[16];
    int tid = threadIdx.x;
    float v = ema_num_new[tid];
    float s = v;
    for (int off = 32; off; off >>= 1) s += __shfl_down(s, off, 64);
    if ((tid & 63) == 0) red[tid >> 6] = s;
    __syncthreads();
    if (tid < 16) {
        float t = red[tid];
        for (int off = 8; off; off >>= 1) t += __shfl_down(t, off, 16);
        if (tid == 0) red[0] = t;
    }
    __syncthreads();
    float total = red[0];
    denom[tid] = (v + EPS) / (total + (float)K * EPS) * total;
}

__global__ __launch_bounds__(256) void k_embednew(
    const float* __restrict__ ema_embed_new, const float* __restrict__ denom,
    float* __restrict__ embed_new) {
    int gid = blockIdx.x * 256 + threadIdx.x;  // K*D/4 threads
    int k = gid >> 5;
    int d4 = (gid & 31) << 2;
    float4 v = *(const float4*)&ema_embed_new[(size_t)k * D + d4];
    float s = denom[k];
    float4 o;
    o.x = v.x / s; o.y = v.y / s; o.z = v.z / s; o.w = v.w / s;
    *(float4*)&embed_new[(size_t)k * D + d4] = o;
}

// ---------------------------------------------------------------------------
extern "C" void kernel_launch(void* const* d_in, const int* in_sizes, int n_in,
                              void* d_out, int out_size, void* d_ws,
                              size_t ws_size, hipStream_t stream) {
    const float* x = (const float*)d_in[0];
    const float* embed = (const float*)d_in[1];
    const float* ema_embed = (const float*)d_in[2];
    const float* ema_num = (const float*)d_in[3];

    float* out = (float*)d_out;
    float* quantize = out;                                   // N*D
    float* embed_new = out + (size_t)N_TOTAL * D;            // K*D
    float* ema_num_new = embed_new + (size_t)K * D;          // K
    float* ema_embed_new = ema_num_new + K;                  // K*D

    char* ws = (char*)d_ws;
    unsigned int* ind = (unsigned int*)ws;                   // N u32
    unsigned int* bucket = ind + N_TOTAL;                    // N u32
    unsigned int* rescue_list = bucket + N_TOTAL;            // N u32
    unsigned short* ehi = (unsigned short*)(rescue_list + N_TOTAL);  // K*D u16
    unsigned short* elo = ehi + (size_t)K * D;               // K*D u16
    float* gsum = (float*)(elo + (size_t)K * D);             // K*D f32
    float* e2h = gsum + (size_t)K * D;                       // K f32
    float* denom = e2h + K;                                  // K f32
    unsigned int* counts = (unsigned int*)(denom + K);       // K u32
    unsigned int* cursor = counts + K;                       // K u32
    unsigned int* rescue_cnt = cursor + K;                   // 1 u32

    k_prep<<<K, 128, 0, stream>>>(embed, ehi, elo, e2h);
    k_zero<<<(K * D) / 256, 256, 0, stream>>>(counts, rescue_cnt, gsum);
    k_screen<<<N_TOTAL / 128, 256, 0, stream>>>(
        x, (const uint4*)ehi, (const uint4*)elo, e2h, ind, rescue_cnt,
        rescue_list);
    k_rescue<<<256, 256, 0, stream>>>(rescue_cnt, rescue_list, x, embed, e2h,
                                      ind);
    k_quant<<<(N_TOTAL * 32) / 256, 256, 0, stream>>>(ind, embed, quantize);
    k_count<<<N_TOTAL / 1024, 256, 0, stream>>>(ind, counts);
    k_scan<<<1, K, 0, stream>>>(counts, cursor);
    k_scatter<<<N_TOTAL / 256, 256, 0, stream>>>(ind, cursor, bucket);
    k_sum2<<<N_TOTAL / 128, 128, 0, stream>>>(bucket, x, gsum);
    k_emafin<<<(K * D) / 256, 256, 0, stream>>>(gsum, counts, ema_num,
                                                ema_embed, ema_num_new,
                                                ema_embed_new);
    k_denom<<<1, K, 0, stream>>>(ema_num_new, denom);
    k_embednew<<<(K * D / 4) / 256, 256, 0, stream>>>(ema_embed_new, denom,
                                                      embed_new);
}